// Round 6
// baseline (70.714 us; speedup 1.0000x reference)
//
#include <hip/hip_runtime.h>

typedef __bf16 bhalf;
typedef bhalf bhalf8 __attribute__((ext_vector_type(8)));
typedef float f32x4 __attribute__((ext_vector_type(4)));
typedef unsigned short u16;

__device__ __forceinline__ u16 f2bf(float f) {
  union { float f; unsigned u; } v; v.f = f;
  unsigned r = v.u + 0x7FFFu + ((v.u >> 16) & 1u);
  return (u16)(r >> 16);
}

// XOR swizzle keyed on bits 7-9; involution; <=2-way banks on frag reads.
__device__ __forceinline__ int swz(int L) { return L ^ (((L >> 7) & 7) << 4); }

#define GLL16(gp, lp) __builtin_amdgcn_global_load_lds( \
    (const __attribute__((address_space(1))) unsigned int*)(gp), \
    (__attribute__((address_space(3))) unsigned int*)(lp), 16, 0, 0)

// counted-vmcnt barrier (T4): leave N VMEM ops in flight, drain LDS writes.
#define BARW(n) do { \
    asm volatile("s_waitcnt vmcnt(" #n ") lgkmcnt(0)" ::: "memory"); \
    __builtin_amdgcn_s_barrier(); \
    __builtin_amdgcn_sched_barrier(0); \
  } while (0)

#define W0E (512 * 832)
#define W1E (256 * 512)
#define W2E (16 * 256)

__global__ __launch_bounds__(256) void cvt_weights(
    const float* __restrict__ W0, const float* __restrict__ W1,
    const float* __restrict__ W2,
    u16* __restrict__ W0b, u16* __restrict__ W1b, u16* __restrict__ W2b)
{
  int i = blockIdx.x * 256 + threadIdx.x;
  if (i < W0E) {
    int r = i / 832, k = i - r * 832;
    W0b[i] = (k < 784) ? f2bf(W0[r * 784 + k]) : (u16)0;
    return;
  }
  i -= W0E;
  if (i < W1E) { W1b[i] = f2bf(W1[i]); return; }
  i -= W1E;
  if (i < W2E) {
    int r = i >> 8, c = i & 255;
    W2b[i] = (r < 10) ? f2bf(W2[r * 256 + c]) : (u16)0;
  }
}

// m1 = relu(x @ W0^T) bf16. 128x128 tile, BK=32, 4 waves, 26 steps.
// 2-deep pipeline: A reg-staged (2 sets), B 3-buffer LDS via gll.
// Counted vmcnt(6) at barriers (6 = next-next tile's 2 B-gll + 4 A-loads).
__global__ __launch_bounds__(256, 3) void gemm1(
    const float* __restrict__ x, const u16* __restrict__ Wb, u16* __restrict__ Cp)
{
  __shared__ u16 As[2][4096];   // 8 KB per buffer
  __shared__ u16 Bs[3][4096];   // 8 KB per buffer
  const int t = threadIdx.x, w = t >> 6, lane = t & 63;
  const int bid = blockIdx.x;
  const int rt = (bid & 7) + ((bid >> 5) << 3);   // XCD-aware
  const int ct = (bid >> 3) & 3;
  const size_t rbase = (size_t)rt * 128, cbase = (size_t)ct * 128;
  const int wr = w >> 1, wc = w & 1, fr = lane & 15, fg = lane >> 4;

  int aOff[4], bOff[4];
#pragma unroll
  for (int i = 0; i < 4; ++i) aOff[i] = swz((wr * 64 + i * 16 + fr) * 64 + fg * 16);
#pragma unroll
  for (int j = 0; j < 4; ++j) bOff[j] = swz((wc * 64 + j * 16 + fr) * 64 + fg * 16);

  // B staging: 8KB tile = 2 x 1KB gll per wave; source pre-swizzled
  const u16* bSrc[2]; int bDst[2];
#pragma unroll
  for (int i = 0; i < 2; ++i) {
    int Dl = (w * 128 + i * 64 + lane) * 16;
    int Ul = swz(Dl);
    bSrc[i] = Wb + (cbase + (Ul >> 6)) * 832 + ((Ul & 63) >> 1);
    bDst[i] = (w * 128 + i * 64) * 16;
  }

  // A reg-stage meta: 2 chunks of 16B-bf16-dest (2x f32x4 source reads) per thread
  int aRow[2], aKe[2], aDst[2];
#pragma unroll
  for (int c = 0; c < 2; ++c) {
    int P = c * 4096 + t * 16;
    int Lg = swz(P);
    aRow[c] = Lg >> 6; aKe[c] = (Lg & 63) >> 1; aDst[c] = P;
  }

  f32x4 acc[4][4];
#pragma unroll
  for (int i = 0; i < 4; ++i)
#pragma unroll
    for (int j = 0; j < 4; ++j) acc[i][j] = (f32x4){0.f, 0.f, 0.f, 0.f};

  f32x4 arA[2][2], arB[2][2];   // two static prefetch sets (rule #20: no runtime idx)

  auto loadA = [&](f32x4 ar[2][2], int k0) {
#pragma unroll
    for (int c = 0; c < 2; ++c) {
      int k = k0 + aKe[c];
      int ko = (k < 784) ? k : 0;      // clamp; W0b zero-padded beyond 784
      const float* p = x + (rbase + aRow[c]) * (size_t)784 + ko;
      ar[c][0] = *(const f32x4*)p; ar[c][1] = *(const f32x4*)(p + 4);
    }
  };
  auto cvtStore = [&](f32x4 ar[2][2], u16* dstBase) {
#pragma unroll
    for (int c = 0; c < 2; ++c) {
      bhalf8 v;
#pragma unroll
      for (int j = 0; j < 4; ++j) { v[j] = (bhalf)ar[c][0][j]; v[4 + j] = (bhalf)ar[c][1][j]; }
      *(bhalf8*)((char*)dstBase + aDst[c]) = v;
    }
  };
  auto mmaPhase = [&](const u16* Abuf, const char* Bbuf) {
    bhalf8 af[4], bfv[4];
#pragma unroll
    for (int i = 0; i < 4; ++i) af[i] = *(const bhalf8*)((const char*)Abuf + aOff[i]);
#pragma unroll
    for (int j = 0; j < 4; ++j) bfv[j] = *(const bhalf8*)(Bbuf + bOff[j]);
#pragma unroll
    for (int i = 0; i < 4; ++i)
#pragma unroll
      for (int j = 0; j < 4; ++j)
        acc[i][j] = __builtin_amdgcn_mfma_f32_16x16x32_bf16(af[i], bfv[j], acc[i][j], 0, 0, 0);
  };

  // prologue: tiles 0 and 1 (order matters for vmcnt counting: B then A, per tile)
#pragma unroll
  for (int i = 0; i < 2; ++i) GLL16(bSrc[i], (char*)Bs[0] + bDst[i]);
  loadA(arA, 0);
#pragma unroll
  for (int i = 0; i < 2; ++i) GLL16(bSrc[i] + 32, (char*)Bs[1] + bDst[i]);
  loadA(arB, 32);

  const char* br0 = (const char*)Bs[0];
  const char* br1 = (const char*)Bs[1];
  const char* br2 = (const char*)Bs[2];

  for (int i = 0; i < 13; ++i) {
    const int tt = 2 * i;
    // ---- phase 0 (step tt): compute from As[0], br0 ----
    cvtStore(arA, As[0]);                 // compiler auto-waits arA loads (drains thru tile tt)
    BARW(6);
    if (i < 12) {
      const int k0 = (tt + 2) * 32;
#pragma unroll
      for (int q = 0; q < 2; ++q) GLL16(bSrc[q] + k0, (char*)br2 + bDst[q]);
      loadA(arA, k0);
    }
    mmaPhase(As[0], br0);

    // ---- phase 1 (step tt+1): compute from As[1], br1 ----
    cvtStore(arB, As[1]);
    BARW(6);
    if (i < 12) {
      const int k0 = (tt + 3) * 32;
#pragma unroll
      for (int q = 0; q < 2; ++q) GLL16(bSrc[q] + k0, (char*)br0 + bDst[q]);
      loadA(arB, k0);
    }
    mmaPhase(As[1], br1);

    // rotate: (r0,r1,r2) <- (r2,r0,r1)
    const char* tp = br0; br0 = br2; br2 = br1; br1 = tp;
  }

#pragma unroll
  for (int i = 0; i < 4; ++i)
#pragma unroll
    for (int j = 0; j < 4; ++j)
#pragma unroll
      for (int q = 0; q < 4; ++q) {
        size_t row = rbase + wr * 64 + i * 16 + fg * 4 + q;
        size_t col = cbase + wc * 64 + j * 16 + fr;
        float vv = acc[i][j][q];
        vv = vv > 0.f ? vv : 0.f;
        Cp[row * 512 + col] = f2bf(vv);
      }
}

// Fused layers 2+3: 64 rows x full 256 cols, 8 waves (2x4), BK=32, 16 steps.
// A and B both gll, 3 buffers each, 2-deep counted-vmcnt pipeline.
// Per-step issue: all waves 2 B-gll; waves 0-3 +1 A-gll -> vmcnt(3)/vmcnt(2).
__global__ __launch_bounds__(512, 4) void gemm23(
    const u16* __restrict__ m1, const u16* __restrict__ W1b,
    const u16* __restrict__ W2b, float* __restrict__ out)
{
  __shared__ u16 pool[30720];    // A bufs @0/4096/8192 B; B bufs @12288/28672/45056 B (61440 B)
  __shared__ u16 W2s[16][264];
  const int t = threadIdx.x, w = t >> 6, lane = t & 63;
  const size_t rbase = (size_t)blockIdx.x * 64;
  const int wr = w >> 2, wc = w & 3, fr = lane & 15, fg = lane >> 4;

  // stage W2 once (16x256 = 512 int4 chunks, 512 threads)
  {
    int r = t >> 5, kc = (t & 31) * 8;
    *(int4*)&W2s[r][kc] = *(const int4*)(W2b + r * 256 + kc);
  }

  int aOff[2], bOff[4];
#pragma unroll
  for (int i = 0; i < 2; ++i) aOff[i] = swz((wr * 32 + i * 16 + fr) * 64 + fg * 16);
#pragma unroll
  for (int j = 0; j < 4; ++j) bOff[j] = swz((wc * 64 + j * 16 + fr) * 64 + fg * 16);

  // A tile 64x32 = 4KB: waves 0-3 issue 1 gll each
  const u16* aSrc = nullptr; int aDst = 0;
  if (w < 4) {
    int Dl = (w * 64 + lane) * 16;
    int Ul = swz(Dl);
    aSrc = m1 + (rbase + (Ul >> 6)) * 512 + ((Ul & 63) >> 1);
    aDst = (w * 64) * 16;
  }
  // B tile 256x32 = 16KB: 2 gll per wave
  const u16* bSrc[2]; int bDst[2];
#pragma unroll
  for (int i = 0; i < 2; ++i) {
    int Dl = (w * 128 + i * 64 + lane) * 16;
    int Ul = swz(Dl);
    bSrc[i] = W1b + (Ul >> 6) * 512 + ((Ul & 63) >> 1);
    bDst[i] = (w * 128 + i * 64) * 16;
  }

  f32x4 acc[2][4];
#pragma unroll
  for (int i = 0; i < 2; ++i)
#pragma unroll
    for (int j = 0; j < 4; ++j) acc[i][j] = (f32x4){0.f, 0.f, 0.f, 0.f};

  char* ab0 = (char*)pool;            char* bb0 = (char*)pool + 12288;
  char* ab1 = (char*)pool + 4096;     char* bb1 = (char*)pool + 28672;
  char* ab2 = (char*)pool + 8192;     char* bb2 = (char*)pool + 45056;

  auto stage = [&](char* abuf, char* bbuf, int k0) {
#pragma unroll
    for (int q = 0; q < 2; ++q) GLL16(bSrc[q] + k0, bbuf + bDst[q]);
    if (w < 4) GLL16(aSrc + k0, abuf + aDst);
  };
  auto mmaPhase = [&](const char* Abuf, const char* Bbuf) {
    bhalf8 af[2], bfv[4];
#pragma unroll
    for (int i = 0; i < 2; ++i) af[i] = *(const bhalf8*)(Abuf + aOff[i]);
#pragma unroll
    for (int j = 0; j < 4; ++j) bfv[j] = *(const bhalf8*)(Bbuf + bOff[j]);
#pragma unroll
    for (int i = 0; i < 2; ++i)
#pragma unroll
      for (int j = 0; j < 4; ++j)
        acc[i][j] = __builtin_amdgcn_mfma_f32_16x16x32_bf16(af[i], bfv[j], acc[i][j], 0, 0, 0);
  };

  // prologue: tiles 0, 1
  stage(ab0, bb0, 0);
  stage(ab1, bb1, 32);

  for (int i = 0; i < 8; ++i) {
    // ---- phase 0 (step 2i) ----
    if (w < 4) { asm volatile("s_waitcnt vmcnt(3)" ::: "memory"); }
    else       { asm volatile("s_waitcnt vmcnt(2)" ::: "memory"); }
    __builtin_amdgcn_s_barrier();
    __builtin_amdgcn_sched_barrier(0);
    if (i < 7) stage(ab2, bb2, (2 * i + 2) * 32);
    mmaPhase(ab0, bb0);

    // ---- phase 1 (step 2i+1) ----
    if (i < 7) {
      if (w < 4) { asm volatile("s_waitcnt vmcnt(3)" ::: "memory"); }
      else       { asm volatile("s_waitcnt vmcnt(2)" ::: "memory"); }
    } else {
      asm volatile("s_waitcnt vmcnt(0)" ::: "memory");
    }
    __builtin_amdgcn_s_barrier();
    __builtin_amdgcn_sched_barrier(0);
    if (i < 7) stage(ab0, bb0, (2 * i + 3) * 32);
    mmaPhase(ab1, bb1);

    // rotate both triples: (r0,r1,r2) <- (r2,r0,r1)
    char* tp = ab0; ab0 = ab2; ab2 = ab1; ab1 = tp;
    tp = bb0; bb0 = bb2; bb2 = bb1; bb1 = tp;
  }

  __syncthreads();                       // full drain; staging LDS dead from here
  // m2 = relu(acc) -> bf16 into pool as [64][264]
#pragma unroll
  for (int i = 0; i < 2; ++i)
#pragma unroll
    for (int j = 0; j < 4; ++j)
#pragma unroll
      for (int q = 0; q < 4; ++q) {
        int row = wr * 32 + i * 16 + fg * 4 + q;
        int col = wc * 64 + j * 16 + fr;
        float vv = acc[i][j][q];
        vv = vv > 0.f ? vv : 0.f;
        pool[row * 264 + col] = f2bf(vv);
      }
  __syncthreads();

  // layer 3: waves 0-3 handle rows w*16..w*16+15; K=256 (8 ksubs)
  if (w < 4) {
    f32x4 acc3 = (f32x4){0.f, 0.f, 0.f, 0.f};
    const int arow = w * 16 + fr;
#pragma unroll
    for (int ks = 0; ks < 8; ++ks) {
      bhalf8 a = *(const bhalf8*)&pool[arow * 264 + ks * 32 + fg * 8];
      bhalf8 b = *(const bhalf8*)&W2s[fr][ks * 32 + fg * 8];
      acc3 = __builtin_amdgcn_mfma_f32_16x16x32_bf16(a, b, acc3, 0, 0, 0);
    }
    if (fr < 10) {
#pragma unroll
      for (int q = 0; q < 4; ++q) {
        size_t row = rbase + w * 16 + fg * 4 + q;
        float vv = acc3[q];
        out[row * 10 + fr] = vv > 0.f ? vv : 0.f;
      }
    }
  }
}

extern "C" void kernel_launch(void* const* d_in, const int* in_sizes, int n_in,
                              void* d_out, int out_size, void* d_ws, size_t ws_size,
                              hipStream_t stream) {
  const float* x  = (const float*)d_in[0];
  const float* W0 = (const float*)d_in[1];
  const float* W1 = (const float*)d_in[2];
  const float* W2 = (const float*)d_in[3];
  float* out = (float*)d_out;

  char* ws = (char*)d_ws;
  u16* m1  = (u16*)(ws);                    // 32768x512 bf16 = 33554432 B
  u16* W0b = (u16*)(ws + 33554432);         // 512x832 = 851968 B
  u16* W1b = (u16*)(ws + 34406400);         // 256x512 = 262144 B
  u16* W2b = (u16*)(ws + 34668544);         // 16x256  = 8192 B

  cvt_weights<<<dim3((W0E + W1E + W2E + 255) / 256), dim3(256), 0, stream>>>(
      W0, W1, W2, W0b, W1b, W2b);

  gemm1<<<dim3(1024), dim3(256), 0, stream>>>(x, W0b, m1);
  gemm23<<<dim3(512), dim3(512), 0, stream>>>(m1, W1b, W2b, out);
}